// Round 1
// baseline (1510.201 us; speedup 1.0000x reference)
//
#include <hip/hip_runtime.h>

// OLSTM: T=20 frames, N=50000 nodes, K=10000 active peds/frame
// RNN=128, EMB=64, IN=2, OUT=5, G2=16
#define TT   20
#define NN   50000
#define KK   10000
#define RNN  128
#define EMB  64
#define GG2  16
#define NOUT 5
#define UD   256   // 2*EMB + RNN (concat [ie,te,h])
#define TM   16    // peds per block

__device__ __forceinline__ float sigf(float x)   { return 1.f / (1.f + __expf(-x)); }
__device__ __forceinline__ float tanh_f(float x) { return 2.f / (1.f + __expf(-2.f * x)) - 1.f; }

// Copy initial h/c state into the d_out state region; winner pass-1 for frame 0.
__global__ __launch_bounds__(256) void init_kernel(
    const float* __restrict__ h0, const float* __restrict__ c0,
    const int* __restrict__ idx0,
    float* __restrict__ h_all, float* __restrict__ c_all, int* __restrict__ win0)
{
    int stride = gridDim.x * blockDim.x;
    int i = blockIdx.x * blockDim.x + threadIdx.x;
    for (int p = i; p < NN * RNN; p += stride) { h_all[p] = h0[p]; c_all[p] = c0[p]; }
    for (int p = i; p < KK; p += stride) atomicMax(&win0[idx0[p]], p);
}

// One frame: winners-only compute, in-place h/c update, fused pass-1 for t+1.
__global__ __launch_bounds__(256) void step_kernel(int t,
    const float* __restrict__ input_data, const float* __restrict__ grids,
    const int*   __restrict__ active_idx,
    const float* __restrict__ W_in,  const float* __restrict__ b_in,
    const float* __restrict__ W_obs, const float* __restrict__ b_obs,
    const float* __restrict__ W_ih,  const float* __restrict__ b_ih,
    const float* __restrict__ W_hh,  const float* __restrict__ b_hh,
    const float* __restrict__ W_out, const float* __restrict__ b_out,
    float* __restrict__ outputs, float* __restrict__ h_all, float* __restrict__ c_all,
    int* __restrict__ win_cur, int* __restrict__ win_nxt, int has_next)
{
    __shared__ __align__(16) float u[TM][260];   // [ie(64) te(64) h(128)] + pad
    __shared__ __align__(16) float ct[TM][132];  // cell state tile
    __shared__ __align__(16) float fo[TM][256];  // f,o gate exchange
    __shared__ __align__(16) float hn[TM][132];  // h_new for out-projection
    __shared__ int s_idx[TM];
    __shared__ int s_win[TM];

    const int tid = threadIdx.x;
    const int k0  = blockIdx.x * TM;

    if (tid < TM) {
        int k = k0 + tid;
        if (has_next) {  // pass-1 for next frame into other-parity winner array
            int nidx = active_idx[(t + 1) * KK + k];
            atomicMax(&win_nxt[nidx], (t + 1) * KK + k);
        }
        int node   = active_idx[t * KK + k];
        s_idx[tid] = node;
        s_win[tid] = (win_cur[node] == t * KK + k) ? 1 : 0;
    }
    __syncthreads();

    // ---- gather h, c (coalesced 512B rows) ----
    for (int m = 0; m < TM; ++m) {
        int node = s_idx[m];
        if (tid < RNN) u[m][128 + tid]  = h_all[node * RNN + tid];
        else           ct[m][tid - RNN] = c_all[node * RNN + (tid - RNN)];
    }
    // ---- input & tensor embeddings: u[m][0:64]=relu(x@W_in+b), u[m][64:128]=relu(obs@W_obs+b) ----
    {
        int e  = tid & 63;
        int mg = tid >> 6;  // 0..3
        for (int pass = 0; pass < 4; ++pass) {
            int m    = pass * 4 + mg;
            int node = s_idx[m];
            float x0 = input_data[(t * NN + node) * 2 + 0];
            float x1 = input_data[(t * NN + node) * 2 + 1];
            u[m][e] = fmaxf(fmaf(x0, W_in[e], fmaf(x1, W_in[64 + e], b_in[e])), 0.f);
            float a = b_obs[e];
            const float* gb = grids + ((long)t * KK + (k0 + m)) * GG2;
            #pragma unroll
            for (int g = 0; g < GG2; ++g) a = fmaf(gb[g], W_obs[g * EMB + e], a);
            u[m][64 + e] = fmaxf(a, 0.f);
        }
    }
    __syncthreads();

    // ---- GEMM: gates[m][g] = sum_k u[m][k]*W[k][g], W = [W_ih; W_hh] (256x512) ----
    const int g0 = tid, g1 = tid + 256;
    float acc0[TM], acc1[TM];
    #pragma unroll
    for (int m = 0; m < TM; ++m) { acc0[m] = 0.f; acc1[m] = 0.f; }
    for (int kk = 0; kk < UD; kk += 4) {
        const float* Wr = (kk < 128) ? (W_ih + kk * 512) : (W_hh + (kk - 128) * 512);
        float wa0 = Wr[g0],        wb0 = Wr[g1];
        float wa1 = Wr[512 + g0],  wb1 = Wr[512 + g1];
        float wa2 = Wr[1024 + g0], wb2 = Wr[1024 + g1];
        float wa3 = Wr[1536 + g0], wb3 = Wr[1536 + g1];
        #pragma unroll
        for (int m = 0; m < TM; ++m) {
            float4 uv = *(const float4*)&u[m][kk];
            acc0[m] = fmaf(uv.x, wa0, acc0[m]); acc0[m] = fmaf(uv.y, wa1, acc0[m]);
            acc0[m] = fmaf(uv.z, wa2, acc0[m]); acc0[m] = fmaf(uv.w, wa3, acc0[m]);
            acc1[m] = fmaf(uv.x, wb0, acc1[m]); acc1[m] = fmaf(uv.y, wb1, acc1[m]);
            acc1[m] = fmaf(uv.z, wb2, acc1[m]); acc1[m] = fmaf(uv.w, wb3, acc1[m]);
        }
    }
    float bias0 = b_ih[g0] + b_hh[g0];
    float bias1 = b_ih[g1] + b_hh[g1];
    #pragma unroll
    for (int m = 0; m < TM; ++m) { acc0[m] += bias0; acc1[m] += bias1; }

    // threads 0..127 hold i (g0) and g (g1) for row r=tid; 128..255 hold f and o for row tid-128
    if (tid >= 128) {
        int r = tid - 128;
        #pragma unroll
        for (int m = 0; m < TM; ++m) { fo[m][r] = acc0[m]; fo[m][128 + r] = acc1[m]; }
    }
    __syncthreads();
    if (tid < 128) {
        int r = tid;
        for (int m = 0; m < TM; ++m) {
            float iv = sigf(acc0[m]);
            float gv = tanh_f(acc1[m]);
            float fv = sigf(fo[m][r]);
            float ov = sigf(fo[m][128 + r]);
            float cn = fmaf(fv, ct[m][r], iv * gv);
            float hv = ov * tanh_f(cn);
            hn[m][r] = hv;
            if (s_win[m]) {  // winners-only in-place state update (race-free: unique node)
                int node = s_idx[m];
                h_all[node * RNN + r] = hv;
                c_all[node * RNN + r] = cn;
            }
        }
    }
    __syncthreads();
    // ---- out projection: out[m][o] = hn[m]@W_out[:,o] + b_out[o] ----
    if (tid < TM * NOUT) {
        int m = tid / NOUT, o = tid % NOUT;
        if (s_win[m]) {
            float a = b_out[o];
            for (int r = 0; r < RNN; ++r) a = fmaf(hn[m][r], W_out[r * NOUT + o], a);
            outputs[((long)t * NN + s_idx[m]) * NOUT + o] = a;
        }
    }
}

extern "C" void kernel_launch(void* const* d_in, const int* in_sizes, int n_in,
                              void* d_out, int out_size, void* d_ws, size_t ws_size,
                              hipStream_t stream) {
    const float* input_data = (const float*)d_in[0];
    const float* grids      = (const float*)d_in[1];
    const float* h0         = (const float*)d_in[2];
    const float* c0         = (const float*)d_in[3];
    const int*   active_idx = (const int*)d_in[4];
    const float* W_in  = (const float*)d_in[5];
    const float* b_in  = (const float*)d_in[6];
    const float* W_obs = (const float*)d_in[7];
    const float* b_obs = (const float*)d_in[8];
    const float* W_ih  = (const float*)d_in[9];
    const float* b_ih  = (const float*)d_in[10];
    const float* W_hh  = (const float*)d_in[11];
    const float* b_hh  = (const float*)d_in[12];
    const float* W_out = (const float*)d_in[13];
    const float* b_out = (const float*)d_in[14];

    // d_out layout: outputs[T*N*5] | h_fin[N*128] | c_fin[N*128] — state lives in place.
    float* outputs = (float*)d_out;
    float* h_all   = outputs + (size_t)TT * NN * NOUT;
    float* c_all   = h_all + (size_t)NN * RNN;
    int*   win     = (int*)d_ws;  // two ping-pong winner arrays of N ints

    hipMemsetAsync(outputs, 0, (size_t)TT * NN * NOUT * sizeof(float), stream);
    hipMemsetAsync(win, 0xFF, (size_t)2 * NN * sizeof(int), stream);  // -1 everywhere
    init_kernel<<<1024, 256, 0, stream>>>(h0, c0, active_idx, h_all, c_all, win);

    for (int t = 0; t < TT; ++t) {
        int* wc = win + (t & 1) * NN;
        int* wn = win + ((t + 1) & 1) * NN;
        step_kernel<<<KK / TM, 256, 0, stream>>>(t, input_data, grids, active_idx,
            W_in, b_in, W_obs, b_obs, W_ih, b_ih, W_hh, b_hh, W_out, b_out,
            outputs, h_all, c_all, wc, wn, (t < TT - 1) ? 1 : 0);
    }
}

// Round 2
// 922.866 us; speedup vs baseline: 1.6364x; 1.6364x over previous
//
#include <hip/hip_runtime.h>

// OLSTM: T=20 frames, N=50000 nodes, K=10000 active peds/frame
// RNN=128, EMB=64, IN=2, OUT=5, G2=16
#define TT   20
#define NN   50000
#define KK   10000
#define RNN  128
#define EMB  64
#define GG2  16
#define NOUT 5
#define MPB  32                      // peds per block
#define NBLK ((KK + MPB - 1) / MPB)  // 313

typedef __attribute__((ext_vector_type(8))) short bf16x8;
typedef __attribute__((ext_vector_type(4))) float f32x4;

__device__ __forceinline__ unsigned short f2b(float x) {  // fp32 -> bf16 bits, RNE
    union { float f; unsigned u; } v; v.f = x;
    return (unsigned short)((v.u + 0x7FFF + ((v.u >> 16) & 1)) >> 16);
}
__device__ __forceinline__ unsigned pack2(float a, float b) {
    return (unsigned)f2b(a) | ((unsigned)f2b(b) << 16);
}
__device__ __forceinline__ float sigf(float x)   { return 1.f / (1.f + __expf(-x)); }
__device__ __forceinline__ float tanh_f(float x) { return 2.f / (1.f + __expf(-2.f * x)) - 1.f; }

// Build bf16 transposed+permuted weights Wt[col'][k] (512x256) and fused bias.
// col' mapping: w=col'>>7, cc=col'&127, ni=cc>>4, cl=cc&15, gate=ni&3,
//               r=32w+16*(ni>>2)+cl, orig col = 128*gate + r.
// => wave w's n-tiles hold i,f,g,o (ni&3) for its own rnn units — LSTM is lane-local.
__global__ __launch_bounds__(256) void prep_kernel(
    const float* __restrict__ Wih, const float* __restrict__ Whh,
    const float* __restrict__ bih, const float* __restrict__ bhh,
    unsigned short* __restrict__ Wt, float* __restrict__ biasp)
{
    int cp = blockIdx.x;       // 0..511
    int k  = threadIdx.x;      // 0..255
    int w = cp >> 7, cc = cp & 127, ni = cc >> 4, cl = cc & 15;
    int gate = ni & 3;
    int r = 32 * w + ((ni >> 2) << 4) + cl;
    int oc = 128 * gate + r;
    float v = (k < 128) ? Wih[k * 512 + oc] : Whh[(k - 128) * 512 + oc];
    Wt[cp * 256 + k] = f2b(v);
    if (k == 0) biasp[cp] = bih[oc] + bhh[oc];
}

// Copy initial h/c into d_out state region; winner pass-1 for frame 0.
__global__ __launch_bounds__(256) void init_kernel(
    const float* __restrict__ h0, const float* __restrict__ c0,
    const int* __restrict__ idx0,
    float* __restrict__ h_all, float* __restrict__ c_all, int* __restrict__ win0)
{
    int stride = gridDim.x * blockDim.x;
    int i = blockIdx.x * blockDim.x + threadIdx.x;
    for (int p = i; p < NN * RNN; p += stride) { h_all[p] = h0[p]; c_all[p] = c0[p]; }
    for (int p = i; p < KK; p += stride) atomicMax(&win0[idx0[p]], p);
}

__global__ __launch_bounds__(256) void step_kernel(int t,
    const float* __restrict__ input_data, const float* __restrict__ grids,
    const int*   __restrict__ active_idx,
    const float* __restrict__ W_in,  const float* __restrict__ b_in,
    const float* __restrict__ W_obs, const float* __restrict__ b_obs,
    const unsigned short* __restrict__ Wt, const float* __restrict__ biasp,
    const float* __restrict__ W_out, const float* __restrict__ b_out,
    float* __restrict__ outputs, float* __restrict__ h_all, float* __restrict__ c_all,
    int* __restrict__ win_cur, int* __restrict__ win_nxt, int has_next)
{
    __shared__ unsigned short uS[MPB][264];  // [ie(64) te(64) h(128)] bf16, pad->2-way banks
    __shared__ float cS[MPB][132];           // cell state fp32
    __shared__ int s_idx[MPB];
    __shared__ int s_win[MPB];

    const int tid = threadIdx.x;
    const int k0  = blockIdx.x * MPB;

    if (tid < MPB) {
        int k = k0 + tid;
        int node = 0, wn = 0;
        if (k < KK) {
            if (has_next)  // fused pass-1 for next frame (other-parity winner array)
                atomicMax(&win_nxt[active_idx[(t + 1) * KK + k]], (t + 1) * KK + k);
            node = active_idx[t * KK + k];
            wn = (win_cur[node] == t * KK + k) ? 1 : 0;
        }
        s_idx[tid] = node; s_win[tid] = wn;
    }
    __syncthreads();

    // ---- gather h (->bf16) and c (fp32); 8 threads per ped row ----
    {
        int m = tid >> 3, l8 = tid & 7;
        int node = s_idx[m];
        const float4* hp = (const float4*)(h_all + (size_t)node * RNN + l8 * 16);
        const float4* cp = (const float4*)(c_all + (size_t)node * RNN + l8 * 16);
        float4 h0v = hp[0], h1v = hp[1], h2v = hp[2], h3v = hp[3];
        unsigned* du = (unsigned*)&uS[m][128 + l8 * 16];
        du[0] = pack2(h0v.x, h0v.y); du[1] = pack2(h0v.z, h0v.w);
        du[2] = pack2(h1v.x, h1v.y); du[3] = pack2(h1v.z, h1v.w);
        du[4] = pack2(h2v.x, h2v.y); du[5] = pack2(h2v.z, h2v.w);
        du[6] = pack2(h3v.x, h3v.y); du[7] = pack2(h3v.z, h3v.w);
        float4* dc = (float4*)&cS[m][l8 * 16];
        dc[0] = cp[0]; dc[1] = cp[1]; dc[2] = cp[2]; dc[3] = cp[3];
    }
    // ---- embeddings: uS[m][0:64]=relu(x@W_in+b) bf16, uS[m][64:128]=relu(obs@W_obs+b) ----
    {
        int m = tid >> 3, e0 = (tid & 7) * 8;
        int node = s_idx[m];
        float x0 = input_data[((size_t)t * NN + node) * 2 + 0];
        float x1 = input_data[((size_t)t * NN + node) * 2 + 1];
        int kg = k0 + m; if (kg >= KK) kg = 0;
        const float4* gb = (const float4*)(grids + ((size_t)t * KK + kg) * GG2);
        float4 g0 = gb[0], g1 = gb[1], g2 = gb[2], g3 = gb[3];
        float gv[16] = {g0.x,g0.y,g0.z,g0.w, g1.x,g1.y,g1.z,g1.w,
                        g2.x,g2.y,g2.z,g2.w, g3.x,g3.y,g3.z,g3.w};
        float ie[8], te[8];
        #pragma unroll
        for (int j = 0; j < 8; ++j) {
            int e = e0 + j;
            ie[j] = fmaxf(fmaf(x0, W_in[e], fmaf(x1, W_in[64 + e], b_in[e])), 0.f);
            float a = b_obs[e];
            #pragma unroll
            for (int gg = 0; gg < GG2; ++gg) a = fmaf(gv[gg], W_obs[gg * EMB + e], a);
            te[j] = fmaxf(a, 0.f);
        }
        unsigned* di = (unsigned*)&uS[m][e0];
        unsigned* dt = (unsigned*)&uS[m][64 + e0];
        #pragma unroll
        for (int j = 0; j < 4; ++j) {
            di[j] = pack2(ie[2 * j], ie[2 * j + 1]);
            dt[j] = pack2(te[2 * j], te[2 * j + 1]);
        }
    }
    __syncthreads();

    // ---- gates GEMM via MFMA: wave w covers permuted cols [128w,128w+128) ----
    const int w = tid >> 6, lane = tid & 63;
    const int cl = lane & 15, kq = lane >> 4;
    f32x4 acc[2][8];
    #pragma unroll
    for (int ni = 0; ni < 8; ++ni) {
        float bv = biasp[128 * w + 16 * ni + cl];
        acc[0][ni] = (f32x4){bv, bv, bv, bv};
        acc[1][ni] = acc[0][ni];
    }
    const unsigned short* Wb = Wt + ((size_t)(128 * w + cl)) * 256 + kq * 8;
    #pragma unroll
    for (int ks = 0; ks < 8; ++ks) {
        const int kk = ks * 32;
        bf16x8 a0 = *(const bf16x8*)&uS[cl][kk + kq * 8];
        bf16x8 a1 = *(const bf16x8*)&uS[16 + cl][kk + kq * 8];
        #pragma unroll
        for (int ni = 0; ni < 8; ++ni) {
            bf16x8 b = *(const bf16x8*)(Wb + ni * 16 * 256 + kk);
            acc[0][ni] = __builtin_amdgcn_mfma_f32_16x16x32_bf16(a0, b, acc[0][ni], 0, 0, 0);
            acc[1][ni] = __builtin_amdgcn_mfma_f32_16x16x32_bf16(a1, b, acc[1][ni], 0, 0, 0);
        }
    }

    // ---- LSTM: lane-local i,f,g,o thanks to the column permutation ----
    // acc[mi][4*rg+gate][reg] is gate `gate` of ped m=16mi+4kq+reg, rnn unit r=32w+16rg+cl
    #pragma unroll
    for (int mi = 0; mi < 2; ++mi) {
        #pragma unroll
        for (int rg = 0; rg < 2; ++rg) {
            #pragma unroll
            for (int reg = 0; reg < 4; ++reg) {
                float iv = acc[mi][4 * rg + 0][reg];
                float fv = acc[mi][4 * rg + 1][reg];
                float gv = acc[mi][4 * rg + 2][reg];
                float ov = acc[mi][4 * rg + 3][reg];
                int m = 16 * mi + 4 * kq + reg;
                int r = 32 * w + 16 * rg + cl;
                float cn = fmaf(sigf(fv), cS[m][r], sigf(iv) * tanh_f(gv));
                float hv = sigf(ov) * tanh_f(cn);
                if (s_win[m]) {  // winners-only in-place state update (unique node/frame)
                    int node = s_idx[m];
                    h_all[(size_t)node * RNN + r] = hv;
                    c_all[(size_t)node * RNN + r] = cn;
                }
            }
        }
    }
    __syncthreads();  // winner h_all writes visible block-wide

    // ---- out projection (winners only), reading back L1-hot h rows ----
    if (tid < MPB * NOUT) {
        int m = tid / NOUT, o = tid % NOUT;
        if (s_win[m]) {
            int node = s_idx[m];
            const float* hp = h_all + (size_t)node * RNN;
            float a0 = b_out[o], a1 = 0.f, a2 = 0.f, a3 = 0.f;
            for (int r = 0; r < RNN; r += 4) {
                a0 = fmaf(hp[r],     W_out[(r)     * NOUT + o], a0);
                a1 = fmaf(hp[r + 1], W_out[(r + 1) * NOUT + o], a1);
                a2 = fmaf(hp[r + 2], W_out[(r + 2) * NOUT + o], a2);
                a3 = fmaf(hp[r + 3], W_out[(r + 3) * NOUT + o], a3);
            }
            outputs[((size_t)t * NN + node) * NOUT + o] = (a0 + a1) + (a2 + a3);
        }
    }
}

extern "C" void kernel_launch(void* const* d_in, const int* in_sizes, int n_in,
                              void* d_out, int out_size, void* d_ws, size_t ws_size,
                              hipStream_t stream) {
    const float* input_data = (const float*)d_in[0];
    const float* grids      = (const float*)d_in[1];
    const float* h0         = (const float*)d_in[2];
    const float* c0         = (const float*)d_in[3];
    const int*   active_idx = (const int*)d_in[4];
    const float* W_in  = (const float*)d_in[5];
    const float* b_in  = (const float*)d_in[6];
    const float* W_obs = (const float*)d_in[7];
    const float* b_obs = (const float*)d_in[8];
    const float* W_ih  = (const float*)d_in[9];
    const float* b_ih  = (const float*)d_in[10];
    const float* W_hh  = (const float*)d_in[11];
    const float* b_hh  = (const float*)d_in[12];
    const float* W_out = (const float*)d_in[13];
    const float* b_out = (const float*)d_in[14];

    // d_out: outputs[T*N*5] | h_fin[N*128] | c_fin[N*128]
    float* outputs = (float*)d_out;
    float* h_all   = outputs + (size_t)TT * NN * NOUT;
    float* c_all   = h_all + (size_t)NN * RNN;

    // d_ws: win[2*N] ints (400000 B) | Wt bf16 512x256 (262144 B) | biasp (2048 B)
    int* win = (int*)d_ws;
    unsigned short* Wt = (unsigned short*)((char*)d_ws + (size_t)2 * NN * sizeof(int));
    float* biasp = (float*)((char*)d_ws + (size_t)2 * NN * sizeof(int) + 512 * 256 * sizeof(unsigned short));

    hipMemsetAsync(outputs, 0, (size_t)TT * NN * NOUT * sizeof(float), stream);
    hipMemsetAsync(win, 0xFF, (size_t)2 * NN * sizeof(int), stream);
    prep_kernel<<<512, 256, 0, stream>>>(W_ih, W_hh, b_ih, b_hh, Wt, biasp);
    init_kernel<<<1024, 256, 0, stream>>>(h0, c0, active_idx, h_all, c_all, win);

    for (int t = 0; t < TT; ++t) {
        int* wc = win + (t & 1) * NN;
        int* wn = win + ((t + 1) & 1) * NN;
        step_kernel<<<NBLK, 256, 0, stream>>>(t, input_data, grids, active_idx,
            W_in, b_in, W_obs, b_obs, Wt, biasp, W_out, b_out,
            outputs, h_all, c_all, wc, wn, (t < TT - 1) ? 1 : 0);
    }
}

// Round 3
// 884.686 us; speedup vs baseline: 1.7070x; 1.0432x over previous
//
#include <hip/hip_runtime.h>

// OLSTM: T=20 frames, N=50000 nodes, K=10000 active peds/frame
// RNN=128, EMB=64, IN=2, OUT=5, G2=16
#define TT   20
#define NN   50000
#define KK   10000
#define RNN  128
#define EMB  64
#define GG2  16
#define NOUT 5
#define MPB  16              // peds per block
#define NTHR 512             // 8 waves
#define NBLK (KK / MPB)      // 625 blocks -> ~2.4 blocks/CU, ~19 waves/CU

typedef __attribute__((ext_vector_type(8))) short bf16x8;
typedef __attribute__((ext_vector_type(4))) float f32x4;

__device__ __forceinline__ unsigned short f2b(float x) {  // fp32 -> bf16 bits, RNE
    union { float f; unsigned u; } v; v.f = x;
    return (unsigned short)((v.u + 0x7FFF + ((v.u >> 16) & 1)) >> 16);
}
__device__ __forceinline__ unsigned pack2(float a, float b) {
    return (unsigned)f2b(a) | ((unsigned)f2b(b) << 16);
}
__device__ __forceinline__ float sigf(float x)   { return 1.f / (1.f + __expf(-x)); }
__device__ __forceinline__ float tanh_f(float x) { return 2.f / (1.f + __expf(-2.f * x)) - 1.f; }

// bf16 transposed+permuted weights Wt[col'][k] (512x256) + fused bias.
// col' = 64*w + 16*ni + cl  ->  gate=ni, r=16*w+cl, orig col = 128*gate + r.
// => wave w's 4 n-tiles are exactly i,f,g,o for its 16 rnn units (lane-local LSTM).
__global__ __launch_bounds__(256) void prep_kernel(
    const float* __restrict__ Wih, const float* __restrict__ Whh,
    const float* __restrict__ bih, const float* __restrict__ bhh,
    unsigned short* __restrict__ Wt, float* __restrict__ biasp)
{
    int cp = blockIdx.x;       // 0..511 (permuted col)
    int k  = threadIdx.x;      // 0..255
    int w = cp >> 6, rem = cp & 63, ni = rem >> 4, cl = rem & 15;
    int oc = 128 * ni + 16 * w + cl;
    float v = (k < 128) ? Wih[k * 512 + oc] : Whh[(k - 128) * 512 + oc];
    Wt[cp * 256 + k] = f2b(v);
    if (k == 0) biasp[cp] = bih[oc] + bhh[oc];
}

// Copy initial h/c into d_out state region; winner pass-1 for frame 0.
__global__ __launch_bounds__(256) void init_kernel(
    const float* __restrict__ h0, const float* __restrict__ c0,
    const int* __restrict__ idx0,
    float* __restrict__ h_all, float* __restrict__ c_all, int* __restrict__ win0)
{
    int stride = gridDim.x * blockDim.x;
    int i = blockIdx.x * blockDim.x + threadIdx.x;
    for (int p = i; p < NN * RNN; p += stride) { h_all[p] = h0[p]; c_all[p] = c0[p]; }
    for (int p = i; p < KK; p += stride) atomicMax(&win0[idx0[p]], p);
}

__global__ __launch_bounds__(NTHR, 4) void step_kernel(int t,
    const float* __restrict__ input_data, const float* __restrict__ grids,
    const int*   __restrict__ active_idx,
    const float* __restrict__ W_in,  const float* __restrict__ b_in,
    const float* __restrict__ W_obs, const float* __restrict__ b_obs,
    const unsigned short* __restrict__ Wt, const float* __restrict__ biasp,
    const float* __restrict__ W_out, const float* __restrict__ b_out,
    float* __restrict__ outputs, float* __restrict__ h_all, float* __restrict__ c_all,
    int* __restrict__ win_cur, int* __restrict__ win_nxt, int has_next)
{
    __shared__ unsigned short uS[MPB][264];  // [ie(64) te(64) h(128)] bf16
    __shared__ float cS[MPB][132];           // cell state fp32; reused as h_new after LSTM
    __shared__ float gS[MPB][GG2];           // staged grid rows
    __shared__ int s_idx[MPB];
    __shared__ int s_win[MPB];

    const int tid = threadIdx.x;
    const int k0  = blockIdx.x * MPB;

    // ---- phase 0: winner flags + grid staging ----
    if (tid < MPB) {
        int k = k0 + tid;
        if (has_next)  // fused pass-1 for next frame (other-parity winner array)
            atomicMax(&win_nxt[active_idx[(t + 1) * KK + k]], (t + 1) * KK + k);
        int node   = active_idx[t * KK + k];
        s_idx[tid] = node;
        s_win[tid] = (win_cur[node] == t * KK + k) ? 1 : 0;
    }
    if (tid < MPB * GG2) {  // 256 threads, coalesced 1 KB
        int m = tid >> 4, g = tid & 15;
        gS[m][g] = grids[((size_t)t * KK + k0 + m) * GG2 + g];
    }
    __syncthreads();

    // ---- phase 1: gather h (->bf16) + c (fp32), 32 threads/ped, coalesced ----
    {
        int m = tid >> 5, l = tid & 31;
        int node = s_idx[m];
        float4 hv = *(const float4*)(h_all + (size_t)node * RNN + l * 4);
        float4 cv = *(const float4*)(c_all + (size_t)node * RNN + l * 4);
        unsigned* du = (unsigned*)&uS[m][128 + l * 4];
        du[0] = pack2(hv.x, hv.y);
        du[1] = pack2(hv.z, hv.w);
        *(float4*)&cS[m][l * 4] = cv;
    }
    // ---- embeddings: 32 threads/ped, 2 cols each ----
    {
        int m = tid >> 5, e0 = (tid & 31) * 2;
        int node = s_idx[m];
        float x0 = input_data[((size_t)t * NN + node) * 2 + 0];
        float x1 = input_data[((size_t)t * NN + node) * 2 + 1];
        float i0 = fmaxf(fmaf(x0, W_in[e0],     fmaf(x1, W_in[64 + e0],     b_in[e0])),     0.f);
        float i1 = fmaxf(fmaf(x0, W_in[e0 + 1], fmaf(x1, W_in[64 + e0 + 1], b_in[e0 + 1])), 0.f);
        float a0 = b_obs[e0], a1 = b_obs[e0 + 1];
        #pragma unroll
        for (int g = 0; g < GG2; ++g) {
            float gv = gS[m][g];
            a0 = fmaf(gv, W_obs[g * EMB + e0],     a0);
            a1 = fmaf(gv, W_obs[g * EMB + e0 + 1], a1);
        }
        *(unsigned*)&uS[m][e0]      = pack2(i0, i1);
        *(unsigned*)&uS[m][64 + e0] = pack2(fmaxf(a0, 0.f), fmaxf(a1, 0.f));
    }
    __syncthreads();

    // ---- gates GEMM via MFMA: wave w covers permuted cols [64w, 64w+64) ----
    const int w = tid >> 6, lane = tid & 63;
    const int cl = lane & 15, kq = lane >> 4;
    f32x4 acc[4];
    #pragma unroll
    for (int ni = 0; ni < 4; ++ni) {
        float bv = biasp[64 * w + 16 * ni + cl];
        acc[ni] = (f32x4){bv, bv, bv, bv};
    }
    const unsigned short* Wb = Wt + ((size_t)(64 * w + cl)) * 256 + kq * 8;
    #pragma unroll
    for (int ks = 0; ks < 8; ++ks) {
        const int kk = ks * 32;
        bf16x8 a = *(const bf16x8*)&uS[cl][kk + kq * 8];
        #pragma unroll
        for (int ni = 0; ni < 4; ++ni) {
            bf16x8 b = *(const bf16x8*)(Wb + (size_t)ni * 16 * 256 + kk);
            acc[ni] = __builtin_amdgcn_mfma_f32_16x16x32_bf16(a, b, acc[ni], 0, 0, 0);
        }
    }

    // ---- LSTM: lane-local i,f,g,o; ped m = 4*kq+reg, rnn unit r = 16*w+cl ----
    #pragma unroll
    for (int reg = 0; reg < 4; ++reg) {
        float iv = acc[0][reg], fv = acc[1][reg], gv = acc[2][reg], ov = acc[3][reg];
        int m = 4 * kq + reg;
        int r = 16 * w + cl;
        float cn = fmaf(sigf(fv), cS[m][r], sigf(iv) * tanh_f(gv));
        float hv = sigf(ov) * tanh_f(cn);
        cS[m][r] = hv;  // exclusive (m,r) per lane: safe in-place reuse as h_new
        if (s_win[m]) { // winners-only in-place state update (unique node/frame)
            int node = s_idx[m];
            h_all[(size_t)node * RNN + r] = hv;
            c_all[(size_t)node * RNN + r] = cn;
        }
    }
    __syncthreads();  // h_new (in cS) visible block-wide

    // ---- out projection (winners only), h_new from LDS ----
    if (tid < MPB * NOUT) {
        int m = tid / NOUT, o = tid - m * NOUT;
        if (s_win[m]) {
            const float* hp = cS[m];
            float a0 = b_out[o], a1 = 0.f, a2 = 0.f, a3 = 0.f;
            for (int r = 0; r < RNN; r += 4) {
                a0 = fmaf(hp[r],     W_out[(r)     * NOUT + o], a0);
                a1 = fmaf(hp[r + 1], W_out[(r + 1) * NOUT + o], a1);
                a2 = fmaf(hp[r + 2], W_out[(r + 2) * NOUT + o], a2);
                a3 = fmaf(hp[r + 3], W_out[(r + 3) * NOUT + o], a3);
            }
            outputs[((size_t)t * NN + s_idx[m]) * NOUT + o] = (a0 + a1) + (a2 + a3);
        }
    }
}

extern "C" void kernel_launch(void* const* d_in, const int* in_sizes, int n_in,
                              void* d_out, int out_size, void* d_ws, size_t ws_size,
                              hipStream_t stream) {
    const float* input_data = (const float*)d_in[0];
    const float* grids      = (const float*)d_in[1];
    const float* h0         = (const float*)d_in[2];
    const float* c0         = (const float*)d_in[3];
    const int*   active_idx = (const int*)d_in[4];
    const float* W_in  = (const float*)d_in[5];
    const float* b_in  = (const float*)d_in[6];
    const float* W_obs = (const float*)d_in[7];
    const float* b_obs = (const float*)d_in[8];
    const float* W_ih  = (const float*)d_in[9];
    const float* b_ih  = (const float*)d_in[10];
    const float* W_hh  = (const float*)d_in[11];
    const float* b_hh  = (const float*)d_in[12];
    const float* W_out = (const float*)d_in[13];
    const float* b_out = (const float*)d_in[14];

    // d_out: outputs[T*N*5] | h_fin[N*128] | c_fin[N*128]
    float* outputs = (float*)d_out;
    float* h_all   = outputs + (size_t)TT * NN * NOUT;
    float* c_all   = h_all + (size_t)NN * RNN;

    // d_ws: win[2*N] ints | Wt bf16 512x256 | biasp[512]
    int* win = (int*)d_ws;
    unsigned short* Wt = (unsigned short*)((char*)d_ws + (size_t)2 * NN * sizeof(int));
    float* biasp = (float*)((char*)d_ws + (size_t)2 * NN * sizeof(int) + 512 * 256 * sizeof(unsigned short));

    hipMemsetAsync(outputs, 0, (size_t)TT * NN * NOUT * sizeof(float), stream);
    hipMemsetAsync(win, 0xFF, (size_t)2 * NN * sizeof(int), stream);
    prep_kernel<<<512, 256, 0, stream>>>(W_ih, W_hh, b_ih, b_hh, Wt, biasp);
    init_kernel<<<1024, 256, 0, stream>>>(h0, c0, active_idx, h_all, c_all, win);

    for (int t = 0; t < TT; ++t) {
        int* wc = win + (t & 1) * NN;
        int* wn = win + ((t + 1) & 1) * NN;
        step_kernel<<<NBLK, NTHR, 0, stream>>>(t, input_data, grids, active_idx,
            W_in, b_in, W_obs, b_obs, Wt, biasp, W_out, b_out,
            outputs, h_all, c_all, wc, wn, (t < TT - 1) ? 1 : 0);
    }
}